// Round 7
// baseline (109.618 us; speedup 1.0000x reference)
//
#include <hip/hip_runtime.h>
#include <hip/hip_bf16.h>

// Co-attention layer, factorized + hand-packed VOP3P (v_pk_*_f32),
// natural packed semantics ONLY (no op_sel — R6's op_sel broadcasts were
// miscompiled/mis-specified and produced wrong results).
//   G_pre[l,r] = x_l*x_r*C1[l,r] + x_l*C2[l,r] + x_r*C3[l,r] + C4[l,r]
//   (C1..C4 weight-only, precomputed into d_ws, pre-scaled by 2*log2e)
//   tanh(g) = 1 - 2*rcp(exp2(g')+1); softmax shift-invariance -> only
//   S = sum rcp(...) accumulated, softmax arg = -2*log2e*S.
// One thread per element; r in pairs. C/dW constants enter pk ops via
// "s" constraints (1 scalar-bus read per instruction).

typedef __attribute__((ext_vector_type(2))) float v2f;

#if __has_builtin(__builtin_amdgcn_exp2f)
#define EXP2F(v) __builtin_amdgcn_exp2f(v)
#else
#define EXP2F(v) exp2f(v)
#endif

#if __has_builtin(__builtin_amdgcn_rcpf)
#define RCPF(v) __builtin_amdgcn_rcpf(v)
#else
#define RCPF(v) (1.0f / (v))
#endif

#define LOG2E 1.4426950408889634f

// ---- VOP3P helpers, natural packed semantics only ----
__device__ __forceinline__ v2f pk_mul_vs(v2f a, v2f s) {   // a * sgpr_pair
    v2f d; asm("v_pk_mul_f32 %0, %1, %2" : "=v"(d) : "v"(a), "s"(s)); return d;
}
__device__ __forceinline__ v2f pk_add_vs(v2f a, v2f s) {   // a + sgpr_pair
    v2f d; asm("v_pk_add_f32 %0, %1, %2" : "=v"(d) : "v"(a), "s"(s)); return d;
}
__device__ __forceinline__ v2f pk_fma_vvv(v2f a, v2f b, v2f c) {
    v2f d; asm("v_pk_fma_f32 %0, %1, %2, %3" : "=v"(d) : "v"(a), "v"(b), "v"(c)); return d;
}
__device__ __forceinline__ v2f pk_fma_vsv(v2f a, v2f s, v2f c) {  // a*sgpr + c
    v2f d; asm("v_pk_fma_f32 %0, %1, %2, %3" : "=v"(d) : "v"(a), "s"(s), "v"(c)); return d;
}
__device__ __forceinline__ v2f pk_add_vv(v2f a, v2f b) {
    v2f d; asm("v_pk_add_f32 %0, %1, %2" : "=v"(d) : "v"(a), "v"(b)); return d;
}
__device__ __forceinline__ v2f pk_mul_vv(v2f a, v2f b) {
    v2f d; asm("v_pk_mul_f32 %0, %1, %2" : "=v"(d) : "v"(a), "v"(b)); return d;
}

// ---------------- setup: C1..C4 (4 x 16 x 16 floats) into d_ws ----------------
__global__ __launch_bounds__(256) void coattn_setup(
    const float* __restrict__ emb_W,
    const float* __restrict__ emb_b,
    const float* __restrict__ M,
    float* __restrict__ C)
{
    const int t = threadIdx.x;          // one thread per (l, r) pair
    const int l = t >> 4;
    const int r = t & 15;

    float MW[8], Mb[8];
    #pragma unroll
    for (int e = 0; e < 8; ++e) {
        float s1 = 0.0f, s2 = 0.0f;
        #pragma unroll
        for (int f = 0; f < 8; ++f) {
            float m = M[e * 8 + f];
            s1 = fmaf(m, emb_W[(16 + r) * 8 + f], s1);
            s2 = fmaf(m, emb_b[(16 + r) * 8 + f], s2);
        }
        MW[e] = s1; Mb[e] = s2;
    }
    float c1 = 0.0f, c2 = 0.0f, c3 = 0.0f, c4 = 0.0f;
    #pragma unroll
    for (int e = 0; e < 8; ++e) {
        float w = emb_W[l * 8 + e];
        float b = emb_b[l * 8 + e];
        c1 = fmaf(w, MW[e], c1);
        c2 = fmaf(w, Mb[e], c2);
        c3 = fmaf(b, MW[e], c3);
        c4 = fmaf(b, Mb[e], c4);
    }
    const float s = 2.0f * LOG2E;
    C[0 * 256 + l * 16 + r] = c1 * s;
    C[1 * 256 + l * 16 + r] = c2 * s;
    C[2 * 256 + l * 16 + r] = c3 * s;
    C[3 * 256 + l * 16 + r] = c4 * s;
}

// ---------------- main: one thread per batch element ----------------
__global__ __launch_bounds__(256) void coattn_kernel(
    const float* __restrict__ x,
    const float* __restrict__ C,
    const float* __restrict__ dW,
    const float* __restrict__ db,
    float* __restrict__ out)
{
    #pragma clang fp contract(off)

    const int i = blockIdx.x * blockDim.x + threadIdx.x;

    // ---- load x[32] as 16 pairs ----
    v2f xv2[16];
    const float4* xp = reinterpret_cast<const float4*>(x + (size_t)i * 32);
    #pragma unroll
    for (int k = 0; k < 8; ++k) {
        float4 v = xp[k];
        xv2[2*k+0] = (v2f){v.x, v.y};
        xv2[2*k+1] = (v2f){v.z, v.w};
    }

    const v2f* Cv = reinterpret_cast<const v2f*>(C);   // table t: +t*128, row l: +l*8

    // ---- G: 16 l x 8 r-pairs, packed; batched rcp (1 per pair) ----
    v2f Scol[8];
    #pragma unroll
    for (int k = 0; k < 8; ++k) Scol[k] = (v2f){0.0f, 0.0f};
    float Srow[16];
    const v2f CLAMP = (v2f){88.0f, 88.0f};

    #pragma unroll
    for (int l = 0; l < 16; ++l) {
        const float xls = xv2[l >> 1][l & 1];
        const v2f xlv = (v2f){xls, xls};
        v2f rs = (v2f){0.0f, 0.0f};
        const v2f* C1p = Cv + 0 * 128 + l * 8;
        const v2f* C2p = Cv + 1 * 128 + l * 8;
        const v2f* C3p = Cv + 2 * 128 + l * 8;
        const v2f* C4p = Cv + 3 * 128 + l * 8;
        #pragma unroll
        for (int k = 0; k < 8; ++k) {
            v2f u = pk_mul_vs(xlv, C1p[k]);
            u = pk_add_vs(u, C3p[k]);                  // u = xl*C1 + C3
            v2f q = pk_mul_vs(xlv, C2p[k]);
            q = pk_add_vs(q, C4p[k]);                  // q = xl*C2 + C4
            v2f g = pk_fma_vvv(xv2[8 + k], u, q);      // g = xr*u + q
            g = __builtin_elementwise_min(g, CLAMP);   // overflow guard for batched rcp
            v2f D;
            D.x = EXP2F(g.x) + 1.0f;
            D.y = EXP2F(g.y) + 1.0f;
            float t = RCPF(D.x * D.y);                 // 1 rcp for both halves
            v2f rc; rc.x = D.y * t; rc.y = D.x * t;
            Scol[k] = pk_add_vv(Scol[k], rc);
            rs = pk_add_vv(rs, rc);
        }
        Srow[l] = rs.x + rs.y;
    }

    // ---- softmaxes (shift-invariant: arg = -2*log2e * S) ----
    const float NSCL = -2.0f * LOG2E;
    v2f av[16];                       // av[0..7]=lr pairs, av[8..15]=rl pairs
    {
        float s = 0.0f;
        #pragma unroll
        for (int k = 0; k < 8; ++k) {
            float e0 = EXP2F(Scol[k].x * NSCL);
            float e1 = EXP2F(Scol[k].y * NSCL);
            av[k] = (v2f){e0, e1};
            s += e0 + e1;
        }
        float inv = RCPF(s);
        #pragma unroll
        for (int k = 0; k < 8; ++k) { av[k].x *= inv; av[k].y *= inv; }
    }
    {
        float s = 0.0f;
        float er[16];
        #pragma unroll
        for (int l = 0; l < 16; ++l) { er[l] = EXP2F(Srow[l] * NSCL); s += er[l]; }
        float inv = RCPF(s);
        #pragma unroll
        for (int m = 0; m < 8; ++m)
            av[8 + m] = (v2f){er[2*m] * inv, er[2*m+1] * inv};
    }

    // ---- dense: o[16] via packed fma; broadcasts via explicit splats ----
    v2f xa2[16];
    #pragma unroll
    for (int m = 0; m < 16; ++m) xa2[m] = pk_mul_vv(xv2[m], av[m]);

    const v2f* dW2  = reinterpret_cast<const v2f*>(dW);   // [32 rows][8 pairs]
    const v2f* db2v = reinterpret_cast<const v2f*>(db);
    v2f o2[8];
    #pragma unroll
    for (int m = 0; m < 8; ++m) o2[m] = db2v[m];

    #pragma unroll
    for (int jp = 0; jp < 16; ++jp) {         // input rows 2jp, 2jp+1
        const v2f xa = xa2[jp];
        const v2f lo = (v2f){xa.x, xa.x};     // explicit splat (v_mov)
        const v2f hi = (v2f){xa.y, xa.y};
        const v2f* w0 = dW2 + (2 * jp + 0) * 8;
        const v2f* w1 = dW2 + (2 * jp + 1) * 8;
        #pragma unroll
        for (int m = 0; m < 8; ++m) {
            o2[m] = pk_fma_vsv(lo, w0[m], o2[m]);   // o += xa.lo * dW[2jp][*]
            o2[m] = pk_fma_vsv(hi, w1[m], o2[m]);   // o += xa.hi * dW[2jp+1][*]
        }
    }

    float4* op = reinterpret_cast<float4*>(out + (size_t)i * 16);
    #pragma unroll
    for (int t = 0; t < 4; ++t) {
        float4 v;
        v.x = fmaxf(o2[2*t+0].x, 0.0f);
        v.y = fmaxf(o2[2*t+0].y, 0.0f);
        v.z = fmaxf(o2[2*t+1].x, 0.0f);
        v.w = fmaxf(o2[2*t+1].y, 0.0f);
        op[t] = v;
    }
}

extern "C" void kernel_launch(void* const* d_in, const int* in_sizes, int n_in,
                              void* d_out, int out_size, void* d_ws, size_t ws_size,
                              hipStream_t stream) {
    const float* x     = (const float*)d_in[0];
    const float* emb_W = (const float*)d_in[1];
    const float* emb_b = (const float*)d_in[2];
    const float* M     = (const float*)d_in[3];
    const float* dW    = (const float*)d_in[4];
    const float* db    = (const float*)d_in[5];
    float* out = (float*)d_out;
    float* C   = (float*)d_ws;          // 4 * 256 floats = 4 KB

    hipLaunchKernelGGL(coattn_setup, dim3(1), dim3(256), 0, stream,
                       emb_W, emb_b, M, C);

    const int B = in_sizes[0] / 32;     // 262144
    dim3 block(256);
    dim3 grid((B + 255) / 256);
    hipLaunchKernelGGL(coattn_kernel, grid, block, 0, stream,
                       x, C, dW, db, out);
}